// Round 4
// baseline (338.551 us; speedup 1.0000x reference)
//
#include <hip/hip_runtime.h>
#include <hip/hip_bf16.h>

// ---------------------------------------------------------------------------
// TinyMNISTNet: out = relu(x @ Wq1^T + b1) @ Wq2^T + b2, ternarized weights.
// x: [65536,784] fp32; W1: [64,784]; b1:[64]; W2:[10,64]; b2:[10]; out fp32 [65536,10].
//
// R6: (a) setup collapsed to ONE parallel sync-free dispatch: each of the 64
//     blocks redundantly computes full sum|W1| (L2/L3-hot, ~1.5us, parallel)
//     so no partial-sum kernel / no inter-kernel dependency; block n quantizes
//     W1 row n; block 0 handles W2 exactly. alpha1 reduction stays in fused
//     epilogue (psm/pcn per-row partials).
//     (b) fused K-loop fully unrolled (static indexing, guards fold away) with
//     x prefetch depth 2 (~800cy in flight vs ~400) to cover HBM-miss latency;
//     zero-LDS direct per-lane A-fragment loads kept from R5.
// ---------------------------------------------------------------------------

typedef __attribute__((ext_vector_type(4))) float f32x4;
typedef __attribute__((ext_vector_type(8))) short s16x8;
typedef __attribute__((ext_vector_type(4))) unsigned int u32x4;

#define K1 784
#define K1_PAD 800          // 25 K-steps of 32
#define NHID 64
#define NOUT 10
#define NSTEP 25

// round-to-nearest-even f32 -> bf16 bits (finite inputs) — epilogue use only
static __device__ __forceinline__ unsigned short f2bf_rne(float f) {
    unsigned int u = __builtin_bit_cast(unsigned int, f);
    unsigned int r = u + 0x7FFFu + ((u >> 16) & 1u);
    return (unsigned short)(r >> 16);
}

// packed f32x2 -> bf16x2 (RNE), gfx950 HW instruction (no builtin; T12/m240)
static __device__ __forceinline__ unsigned int cvt_pk_bf16(float lo, float hi) {
    unsigned int r;
    asm("v_cvt_pk_bf16_f32 %0, %1, %2" : "=v"(r) : "v"(lo), "v"(hi));
    return r;
}

// block-wide f64 sum for 256-thread blocks (4 waves); result valid in all threads
static __device__ double block_sum256(double v, double* red) {
    #pragma unroll
    for (int off = 32; off > 0; off >>= 1) v += __shfl_down(v, off, 64);
    const int w = threadIdx.x >> 6;
    const int lane = threadIdx.x & 63;
    __syncthreads();                 // protect red[] reuse across calls
    if (lane == 0) red[w] = v;
    __syncthreads();
    return red[0] + red[1] + red[2] + red[3];
}

// ---------------------------------------------------------------------------
// Single-dispatch parallel ternarize. 64 blocks x 256 threads.
// Every block computes the FULL sum|W1| itself (reads 200KB; block 0 pulls to
// L2/L3, the rest hit cache) -> identical delta1 everywhere, no cross-block
// sync. Block n quantizes W1 row n and writes per-row psm/pcn partials for the
// fused-kernel alpha1 reduction. Block 0 additionally does W2 end-to-end.
// ---------------------------------------------------------------------------
__global__ __launch_bounds__(256) void tern_all_kernel(
    const float* __restrict__ W1, const float* __restrict__ W2,
    unsigned short* __restrict__ W1q, unsigned short* __restrict__ W2q,
    double* __restrict__ psm, double* __restrict__ pcn,
    double* __restrict__ a2)
{
    __shared__ double red[4];
    const int tid = threadIdx.x;

    // ---- full sum|W1|, redundantly per block (deterministic identical) ----
    double s = 0.0;
    for (int i = tid; i < (NHID * K1) / 4; i += 256) {
        f32x4 v = ((const f32x4*)W1)[i];
        s += (double)fabsf(v[0]) + (double)fabsf(v[1])
           + (double)fabsf(v[2]) + (double)fabsf(v[3]);
    }
    s = block_sum256(s, red);
    const float delta1 = (float)(0.7 * s / (double)(NHID * K1));

    // ---- this block quantizes W1 row n -> padded [800] bf16 signs ----
    const int n = blockIdx.x;
    double sm = 0.0, cn = 0.0;
    for (int k = tid; k < K1_PAD; k += 256) {
        unsigned short q = 0;
        if (k < K1) {
            float w = W1[n * K1 + k];
            float a = fabsf(w);
            if (a > delta1) { q = (w > 0.0f) ? 0x3F80u : 0xBF80u; sm += (double)a; cn += 1.0; }
        }
        W1q[n * K1_PAD + k] = q;
    }
    sm = block_sum256(sm, red);
    cn = block_sum256(cn, red);
    if (tid == 0) { psm[n] = sm; pcn[n] = cn; }

    // ---- block 0: W2 end-to-end (640 floats) ----
    if (blockIdx.x == 0) {
        double s2 = 0.0;
        if (tid < (NOUT * NHID) / 4) {
            f32x4 v = ((const f32x4*)W2)[tid];
            s2 = (double)fabsf(v[0]) + (double)fabsf(v[1])
               + (double)fabsf(v[2]) + (double)fabsf(v[3]);
        }
        s2 = block_sum256(s2, red);
        const float delta2 = (float)(0.7 * s2 / (double)(NOUT * NHID));

        double sm2 = 0.0, cn2 = 0.0;
        for (int i = tid; i < 16 * NHID; i += 256) {
            int r = i >> 6;
            int k = i & 63;
            unsigned short q = 0;
            if (r < NOUT) {
                float w = W2[r * NHID + k];
                float a = fabsf(w);
                if (a > delta2) { q = (w > 0.0f) ? 0x3F80u : 0xBF80u; sm2 += (double)a; cn2 += 1.0; }
            }
            W2q[i] = q;
        }
        sm2 = block_sum256(sm2, red);
        cn2 = block_sum256(cn2, red);
        if (tid == 0) a2[0] = sm2 / fmax(cn2, 1.0);
    }
}

// ---------------------------------------------------------------------------
// Fused 2-layer kernel. 256 threads = 4 waves; each wave: 16 batch rows x all
// 64 hidden features, then 16x10 outputs. Grid: nrows/64.
//
// Layer-1 K-loop (zero LDS, FULLY UNROLLED, prefetch depth 2): MFMA A-layout
// is A[m=lane&15][k=quad*8+j], so lane (quad,low) owns 8 CONSECUTIVE floats of
// row m0+low. Step ks consumes the x-chunk issued at step ks-2 (~2 iterations
// = ~800cy in flight, covering HBM-miss latency). W1q B-fragments prefetched
// 1 step ahead (L2-hot after first block).
//
// Tail (ks=24): cols 784..799 don't exist; the kf<K1 guard (compile-time after
// unroll) zero-fills quads 2-3, and W1q is zero-padded there -> contributes 0.
//
// MFMA 16x16x32 bf16 layouts (m89/m91/m120-verified):
//   A[m=lane&15][k=quad*8+j], B[n=lane&15][k=quad*8+j], C/D: col=lane&15, row=quad*4+reg
// ---------------------------------------------------------------------------
__global__ __launch_bounds__(256) void fused_kernel(
    const float* __restrict__ x,
    const float* __restrict__ b1,
    const float* __restrict__ b2,
    const short* __restrict__ W1q,   // [64][800] bf16 signs
    const short* __restrict__ W2q,   // [16][64]  bf16 signs
    const double* __restrict__ psm,  // [64] per-row kept-sum partials
    const double* __restrict__ pcn,  // [64] per-row kept-count partials
    const double* __restrict__ a2,   // [1] alpha2 (exact)
    float* __restrict__ out)
{
    const int tid  = threadIdx.x;
    const int wave = tid >> 6;
    const int lane = tid & 63;
    const int low  = lane & 15;
    const int quad = lane >> 4;

    const int m0 = blockIdx.x * 64 + wave * 16;

    // per-lane A-fragment base: row m0+low, starting float quad*8
    const float* ga = x + (size_t)(m0 + low) * K1 + quad * 8;

    __shared__ __align__(16) unsigned short h_lds[4][16][72];  // layer-2 A staging

    const short* wbase = W1q + (size_t)low * K1_PAD + quad * 8;

    f32x4 acc[4];
    #pragma unroll
    for (int nt = 0; nt < 4; ++nt) acc[nt] = (f32x4){0.f, 0.f, 0.f, 0.f};

    const f32x4 zero4 = (f32x4){0.f, 0.f, 0.f, 0.f};

    // pipeline regs: cA = chunk for current step, cB = +1, cC = +2 (rotated;
    // full unroll renames the rotation away)
    f32x4 cA0 = *(const f32x4*)(ga);
    f32x4 cA1 = *(const f32x4*)(ga + 4);
    f32x4 cB0 = *(const f32x4*)(ga + 32);
    f32x4 cB1 = *(const f32x4*)(ga + 36);
    f32x4 cC0, cC1;

    s16x8 bf[4], bn[4];
    #pragma unroll
    for (int nt = 0; nt < 4; ++nt)
        bf[nt] = *(const s16x8*)(wbase + (size_t)nt * 16 * K1_PAD);

    #pragma unroll
    for (int ks = 0; ks < NSTEP; ++ks) {
        // issue x-chunk for step ks+2 (two full iterations of latency cover)
        if (ks + 2 < NSTEP) {
            const int kf = (ks + 2) * 32 + quad * 8;
            if (kf < K1) {               // tail step 24: quads 2-3 stay zero
                cC0 = *(const f32x4*)(ga + (ks + 2) * 32);
                cC1 = *(const f32x4*)(ga + (ks + 2) * 32 + 4);
            } else {
                cC0 = zero4; cC1 = zero4;
            }
        } else {
            cC0 = zero4; cC1 = zero4;
        }
        // B fragments for step ks+1 (L2-hot)
        if (ks + 1 < NSTEP) {
            const short* wn = wbase + (ks + 1) * 32;
            #pragma unroll
            for (int nt = 0; nt < 4; ++nt)
                bn[nt] = *(const s16x8*)(wn + (size_t)nt * 16 * K1_PAD);
        }

        // convert current chunk -> A fragment (8 sequential bf16), MFMA
        u32x4 au;
        au[0] = cvt_pk_bf16(cA0[0], cA0[1]);
        au[1] = cvt_pk_bf16(cA0[2], cA0[3]);
        au[2] = cvt_pk_bf16(cA1[0], cA1[1]);
        au[3] = cvt_pk_bf16(cA1[2], cA1[3]);
        s16x8 a = __builtin_bit_cast(s16x8, au);

        #pragma unroll
        for (int nt = 0; nt < 4; ++nt)
            acc[nt] = __builtin_amdgcn_mfma_f32_16x16x32_bf16(a, bf[nt], acc[nt], 0, 0, 0);

        #pragma unroll
        for (int nt = 0; nt < 4; ++nt) bf[nt] = bn[nt];
        cA0 = cB0; cA1 = cB1; cB0 = cC0; cB1 = cC1;
    }

    // ---- alpha1 reduction (per-wave, redundant, L2/L3-hot: 64 doubles each) ----
    double vs = psm[lane], vc = pcn[lane];
    #pragma unroll
    for (int off = 32; off > 0; off >>= 1) {
        vs += __shfl_down(vs, off, 64);
        vc += __shfl_down(vc, off, 64);
    }
    vs = __shfl(vs, 0, 64);
    vc = __shfl(vc, 0, 64);
    const float alpha1 = (float)(vs / fmax(vc, 1.0));
    const float alpha2 = (float)a2[0];

    // ---- epilogue 1: alpha1*acc + b1, relu, bf16 -> LDS (C-layout -> A-layout) ----
    #pragma unroll
    for (int nt = 0; nt < 4; ++nt) {
        const int n = nt * 16 + low;
        const float bias = b1[n];
        #pragma unroll
        for (int r = 0; r < 4; ++r) {
            float hv = fmaxf(0.0f, fmaf(alpha1, acc[nt][r], bias));
            h_lds[wave][quad * 4 + r][n] = f2bf_rne(hv);
        }
    }
    __asm__ volatile("s_waitcnt lgkmcnt(0)" ::: "memory");

    // ---- layer 2: [16x64] x [64x16] via 2 MFMA steps ----
    s16x8 a0 = *(const s16x8*)(&h_lds[wave][low][quad * 8]);
    s16x8 a1 = *(const s16x8*)(&h_lds[wave][low][32 + quad * 8]);
    s16x8 w0 = *(const s16x8*)(W2q + low * 64 + quad * 8);
    s16x8 w1 = *(const s16x8*)(W2q + low * 64 + 32 + quad * 8);

    f32x4 acc2 = (f32x4){0.f, 0.f, 0.f, 0.f};
    acc2 = __builtin_amdgcn_mfma_f32_16x16x32_bf16(a0, w0, acc2, 0, 0, 0);
    acc2 = __builtin_amdgcn_mfma_f32_16x16x32_bf16(a1, w1, acc2, 0, 0, 0);

    // ---- epilogue 2: alpha2*acc2 + b2, store fp32 ----
    if (low < NOUT) {
        const float bias2 = b2[low];
        #pragma unroll
        for (int r = 0; r < 4; ++r) {
            const int row = m0 + quad * 4 + r;
            out[(size_t)row * NOUT + low] = fmaf(alpha2, acc2[r], bias2);
        }
    }
}

// ---------------------------------------------------------------------------
extern "C" void kernel_launch(void* const* d_in, const int* in_sizes, int n_in,
                              void* d_out, int out_size, void* d_ws, size_t ws_size,
                              hipStream_t stream) {
    const float* x  = (const float*)d_in[0];
    const float* W1 = (const float*)d_in[1];
    const float* b1 = (const float*)d_in[2];
    const float* W2 = (const float*)d_in[3];
    const float* b2 = (const float*)d_in[4];
    float* out = (float*)d_out;

    const int nrows = in_sizes[0] / K1;   // 65536

    // ws layout (all 64B-aligned):
    //   [0]      psm[64] doubles     (512B)
    //   [512]    pcn[64] doubles     (512B)
    //   [1024]   a2 double           (64B block)
    //   [1088]   W1q [64*800] ushort (100KB)
    //   then     W2q [16*64] ushort
    char* base = (char*)d_ws;
    double* psm = (double*)(base);
    double* pcn = (double*)(base + 512);
    double* a2  = (double*)(base + 1024);
    unsigned short* W1q = (unsigned short*)(base + 1088);
    unsigned short* W2q = W1q + NHID * K1_PAD;

    tern_all_kernel<<<64, 256, 0, stream>>>(W1, W2, W1q, W2q, psm, pcn, a2);

    const int nblocks = nrows / 64;       // 64 rows per block (16 per wave)
    fused_kernel<<<nblocks, 256, 0, stream>>>(x, b1, b2, (const short*)W1q,
                                              (const short*)W2q, psm, pcn, a2, out);
}

// Round 5
// 306.402 us; speedup vs baseline: 1.1049x; 1.1049x over previous
//
#include <hip/hip_runtime.h>
#include <hip/hip_bf16.h>

// ---------------------------------------------------------------------------
// TinyMNISTNet: out = relu(x @ Wq1^T + b1) @ Wq2^T + b2, ternarized weights.
// x: [65536,784] fp32; W1: [64,784]; b1:[64]; W2:[10,64]; b2:[10]; out fp32 [65536,10].
//
// R7: EXACT revert to the best-measured kernel (R2, 308.7us). R3-R6 explored
// single-block setup (344.8), parallel atomic-free setup + B-prefetch (312.2),
// zero-LDS direct loads (318.2), full-unroll depth-2 prefetch + redundant-sum
// setup (338.6) — all neutral-to-regressive vs this version. The controllable
// ~65us (vs 242us fixed harness fills) is latency-floor-bound; this is the
// best-known configuration, resubmitted as an A/A noise-bound measurement.
// ---------------------------------------------------------------------------

typedef __attribute__((ext_vector_type(4))) float f32x4;
typedef __attribute__((ext_vector_type(8))) short s16x8;
typedef __attribute__((ext_vector_type(4))) short s16x4;

#define K1 784
#define K1_PAD 800          // 25 K-steps of 32
#define NHID 64
#define NOUT 10

// round-to-nearest-even f32 -> bf16 bits (finite inputs)
static __device__ __forceinline__ unsigned short f2bf_rne(float f) {
    unsigned int u = __builtin_bit_cast(unsigned int, f);
    unsigned int r = u + 0x7FFFu + ((u >> 16) & 1u);
    return (unsigned short)(r >> 16);
}

// block-wide f64 sum for 256-thread blocks (4 waves)
static __device__ double block_sum256(double v, double* red) {
    #pragma unroll
    for (int off = 32; off > 0; off >>= 1) v += __shfl_down(v, off, 64);
    const int w = threadIdx.x >> 6;
    const int lane = threadIdx.x & 63;
    __syncthreads();                 // protect red[] reuse across calls
    if (lane == 0) red[w] = v;
    __syncthreads();
    return red[0] + red[1] + red[2] + red[3];
}

// ---------------------------------------------------------------------------
// hdr layout (doubles): [0]=sumabs(W1) [1]=sumabs(W2) [2]=sm1 [3]=cn1 [4]=sm2 [5]=cn2
// ---------------------------------------------------------------------------
__global__ __launch_bounds__(256) void tern_sum_kernel(
    const float* __restrict__ W1, const float* __restrict__ W2,
    double* __restrict__ hdr)
{
    __shared__ double red[4];
    double s = 0.0;
    for (int i = blockIdx.x * 256 + threadIdx.x; i < NHID * K1; i += gridDim.x * 256)
        s += (double)fabsf(W1[i]);
    s = block_sum256(s, red);
    if (threadIdx.x == 0) atomicAdd(&hdr[0], s);

    if (blockIdx.x == 0) {
        double s2 = 0.0;
        for (int i = threadIdx.x; i < NOUT * NHID; i += 256)
            s2 += (double)fabsf(W2[i]);
        s2 = block_sum256(s2, red);
        if (threadIdx.x == 0) atomicAdd(&hdr[1], s2);
    }
}

__global__ __launch_bounds__(256) void tern_quant_kernel(
    const float* __restrict__ W1, const float* __restrict__ W2,
    unsigned short* __restrict__ W1q, unsigned short* __restrict__ W2q,
    double* __restrict__ hdr)
{
    __shared__ double red[4];
    const float delta1 = (float)(0.7 * hdr[0] / (double)(NHID * K1));

    double sm = 0.0, cn = 0.0;
    for (int i = blockIdx.x * 256 + threadIdx.x; i < NHID * K1_PAD; i += gridDim.x * 256) {
        int n = i / K1_PAD;
        int k = i - n * K1_PAD;
        unsigned short v = 0;
        if (k < K1) {
            float w = W1[n * K1 + k];
            float a = fabsf(w);
            if (a > delta1) { v = (w > 0.0f) ? 0x3F80u : 0xBF80u; sm += (double)a; cn += 1.0; }
        }
        W1q[i] = v;
    }
    sm = block_sum256(sm, red);
    cn = block_sum256(cn, red);
    if (threadIdx.x == 0) { atomicAdd(&hdr[2], sm); atomicAdd(&hdr[3], cn); }

    if (blockIdx.x == 0) {
        const float delta2 = (float)(0.7 * hdr[1] / (double)(NOUT * NHID));
        double sm2 = 0.0, cn2 = 0.0;
        for (int i = threadIdx.x; i < 16 * NHID; i += 256) {
            int n = i >> 6;
            int k = i & 63;
            unsigned short v = 0;
            if (n < NOUT) {
                float w = W2[n * NHID + k];
                float a = fabsf(w);
                if (a > delta2) { v = (w > 0.0f) ? 0x3F80u : 0xBF80u; sm2 += (double)a; cn2 += 1.0; }
            }
            W2q[i] = v;
        }
        sm2 = block_sum256(sm2, red);
        cn2 = block_sum256(cn2, red);
        if (threadIdx.x == 0) { atomicAdd(&hdr[4], sm2); atomicAdd(&hdr[5], cn2); }
    }
}

// ---------------------------------------------------------------------------
// Fused 2-layer kernel. 256 threads = 4 waves; each wave: 16 batch rows x all
// 64 hidden features, then 16x10 outputs. Grid: nrows/64.
//
// Per K-step (32 floats/row), each wave stages its 16x32 fp32 tile:
//   sweep0: lane i loads rows m0+(i>>3), 16B at float (i&7)*4   -> 8x128B txns
//   sweep1: same for rows m0+8+(i>>3)
// convert to bf16, write to wave-private LDS (contiguous, conflict-free),
// read back MFMA A-fragments (lane: row=lane&15, k=quad*8). Double-buffered;
// next chunk's global loads issue one full iteration ahead.
//
// MFMA 16x16x32 bf16 layouts (m89/m91/m120-verified):
//   A[m=lane&15][k=quad*8+j], B[n=lane&15][k=quad*8+j], C/D: col=lane&15, row=quad*4+reg
// ---------------------------------------------------------------------------
__global__ __launch_bounds__(256) void fused_kernel(
    const float* __restrict__ x,
    const float* __restrict__ b1,
    const float* __restrict__ b2,
    const short* __restrict__ W1q,   // [64][800] bf16 signs
    const short* __restrict__ W2q,   // [16][64]  bf16 signs
    const double* __restrict__ hdr,
    float* __restrict__ out)
{
    const int tid  = threadIdx.x;
    const int wave = tid >> 6;
    const int lane = tid & 63;
    const int low  = lane & 15;
    const int quad = lane >> 4;

    const int m0 = blockIdx.x * 64 + wave * 16;

    // staging-load role: 8 lanes per row, 16B per lane (contiguous 128B/row)
    const int srow = lane >> 3;      // 0..7
    const int scol = lane & 7;       // *4 floats = *16 bytes
    const float* g0 = x + (size_t)(m0 + srow) * K1 + scol * 4;
    const float* g1 = x + (size_t)(m0 + 8 + srow) * K1 + scol * 4;

    // wave-private double-buffered A-stage: [wave][buf][row 16][k 32] bf16 = 1KB/buf
    __shared__ __align__(16) unsigned short stage[4][2][16][32];
    __shared__ __align__(16) unsigned short h_lds[4][16][72];  // layer-2 A staging

    const short* wbase = W1q + (size_t)low * K1_PAD + quad * 8;

    f32x4 acc[4];
    #pragma unroll
    for (int nt = 0; nt < 4; ++nt) acc[nt] = (f32x4){0.f, 0.f, 0.f, 0.f};

    const f32x4 zero4 = (f32x4){0.f, 0.f, 0.f, 0.f};

    // prologue: load chunk 0
    f32x4 c0 = *(const f32x4*)(g0);
    f32x4 c1 = *(const f32x4*)(g1);

    int buf = 0;
    for (int ks = 0; ks < 25; ++ks) {
        // prefetch next chunk (full iteration of latency hiding)
        f32x4 n0 = zero4, n1 = zero4;
        if (ks < 24) {
            const int kf = (ks + 1) * 32 + scol * 4;
            if (kf < K1) {               // tail chunk 24: only scol<4 valid
                n0 = *(const f32x4*)(g0 + (ks + 1) * 32);
                n1 = *(const f32x4*)(g1 + (ks + 1) * 32);
            }
        }

        // convert current chunk -> bf16, stash to LDS (lane-contiguous b64s)
        s16x4 p0, p1;
        p0[0] = (short)f2bf_rne(c0[0]); p0[1] = (short)f2bf_rne(c0[1]);
        p0[2] = (short)f2bf_rne(c0[2]); p0[3] = (short)f2bf_rne(c0[3]);
        p1[0] = (short)f2bf_rne(c1[0]); p1[1] = (short)f2bf_rne(c1[1]);
        p1[2] = (short)f2bf_rne(c1[2]); p1[3] = (short)f2bf_rne(c1[3]);
        *(s16x4*)&stage[wave][buf][srow][scol * 4]     = p0;
        *(s16x4*)&stage[wave][buf][8 + srow][scol * 4] = p1;

        // wave-private LDS write->cross-lane read: drain DS pipe explicitly
        __asm__ volatile("s_waitcnt lgkmcnt(0)" ::: "memory");

        s16x8 a = *(const s16x8*)&stage[wave][buf][low][quad * 8];
        const short* wk = wbase + ks * 32;
        #pragma unroll
        for (int nt = 0; nt < 4; ++nt) {
            s16x8 b = *(const s16x8*)(wk + (size_t)nt * 16 * K1_PAD);
            acc[nt] = __builtin_amdgcn_mfma_f32_16x16x32_bf16(a, b, acc[nt], 0, 0, 0);
        }

        c0 = n0; c1 = n1; buf ^= 1;
    }

    // ---- epilogue 1: alpha1*acc + b1, relu, bf16 -> LDS (C-layout -> A-layout) ----
    const float alpha1 = (float)(hdr[2] / fmax(hdr[3], 1.0));
    const float alpha2 = (float)(hdr[4] / fmax(hdr[5], 1.0));

    #pragma unroll
    for (int nt = 0; nt < 4; ++nt) {
        const int n = nt * 16 + low;
        const float bias = b1[n];
        #pragma unroll
        for (int r = 0; r < 4; ++r) {
            float hv = fmaxf(0.0f, fmaf(alpha1, acc[nt][r], bias));
            h_lds[wave][quad * 4 + r][n] = f2bf_rne(hv);
        }
    }
    __asm__ volatile("s_waitcnt lgkmcnt(0)" ::: "memory");

    // ---- layer 2: [16x64] x [64x16] via 2 MFMA steps ----
    s16x8 a0 = *(const s16x8*)(&h_lds[wave][low][quad * 8]);
    s16x8 a1 = *(const s16x8*)(&h_lds[wave][low][32 + quad * 8]);
    s16x8 w0 = *(const s16x8*)(W2q + low * 64 + quad * 8);
    s16x8 w1 = *(const s16x8*)(W2q + low * 64 + 32 + quad * 8);

    f32x4 acc2 = (f32x4){0.f, 0.f, 0.f, 0.f};
    acc2 = __builtin_amdgcn_mfma_f32_16x16x32_bf16(a0, w0, acc2, 0, 0, 0);
    acc2 = __builtin_amdgcn_mfma_f32_16x16x32_bf16(a1, w1, acc2, 0, 0, 0);

    // ---- epilogue 2: alpha2*acc2 + b2, store fp32 ----
    if (low < NOUT) {
        const float bias2 = b2[low];
        #pragma unroll
        for (int r = 0; r < 4; ++r) {
            const int row = m0 + quad * 4 + r;
            out[(size_t)row * NOUT + low] = fmaf(alpha2, acc2[r], bias2);
        }
    }
}

// ---------------------------------------------------------------------------
extern "C" void kernel_launch(void* const* d_in, const int* in_sizes, int n_in,
                              void* d_out, int out_size, void* d_ws, size_t ws_size,
                              hipStream_t stream) {
    const float* x  = (const float*)d_in[0];
    const float* W1 = (const float*)d_in[1];
    const float* b1 = (const float*)d_in[2];
    const float* W2 = (const float*)d_in[3];
    const float* b2 = (const float*)d_in[4];
    float* out = (float*)d_out;

    const int nrows = in_sizes[0] / K1;   // 65536

    // ws layout: hdr 6 doubles (64B aligned block) | W1q [64*800] bf16 | W2q [16*64] bf16
    double* hdr = (double*)d_ws;
    unsigned short* W1q = (unsigned short*)((char*)d_ws + 64);
    unsigned short* W2q = W1q + NHID * K1_PAD;

    hipMemsetAsync(d_ws, 0, 64, stream);  // zero atomic accumulators

    tern_sum_kernel<<<64, 256, 0, stream>>>(W1, W2, hdr);
    tern_quant_kernel<<<64, 256, 0, stream>>>(W1, W2, W1q, W2q, hdr);

    const int nblocks = nrows / 64;       // 64 rows per block (16 per wave)
    fused_kernel<<<nblocks, 256, 0, stream>>>(x, b1, b2, (const short*)W1q,
                                              (const short*)W2q, hdr, out);
}